// Round 1
// baseline (146.118 us; speedup 1.0000x reference)
//
#include <hip/hip_runtime.h>

// 4-level hierarchical decomposition:
//   sections = src[:, idx, :]  (B, n_out, K=4, E=128)
//   means    = sections.mean(axis=-2)
//   detail   = sections - means  -> (B, n_out*4, E)
// Each 32-thread group handles one (b, r): lane = float4 column (E/4 = 32).

constexpr int Bc = 2;
constexpr int Ec = 128;
constexpr int Nc = 262144;
constexpr int E4 = Ec / 4;   // 32 float4 per row

__global__ __launch_bounds__(256) void decomp_level_kernel(
    const float4* __restrict__ src,    // (B, n_src, E4)
    const int4*   __restrict__ idx,    // (n_out) int4 (K=4 indices)
    float4*       __restrict__ detail, // (B, n_out*4, E4)
    float4*       __restrict__ means,  // (B, n_out, E4)
    int n_out, int n_src, int lg_nout, int total_rows)
{
    int gid  = blockIdx.x * blockDim.x + threadIdx.x;
    int lane = gid & (E4 - 1);
    int row  = gid >> 5;               // (b * n_out + r)
    if (row >= total_rows) return;
    int b = row >> lg_nout;
    int r = row & (n_out - 1);

    const float4* s = src + (size_t)b * n_src * E4;
    int4 iv = idx[r];

    float4 a0 = s[(size_t)iv.x * E4 + lane];
    float4 a1 = s[(size_t)iv.y * E4 + lane];
    float4 a2 = s[(size_t)iv.z * E4 + lane];
    float4 a3 = s[(size_t)iv.w * E4 + lane];

    float4 m;
    m.x = (a0.x + a1.x + a2.x + a3.x) * 0.25f;
    m.y = (a0.y + a1.y + a2.y + a3.y) * 0.25f;
    m.z = (a0.z + a1.z + a2.z + a3.z) * 0.25f;
    m.w = (a0.w + a1.w + a2.w + a3.w) * 0.25f;

    means[((size_t)b * n_out + r) * E4 + lane] = m;

    size_t dbase = (((size_t)b * n_out + r) * 4) * E4 + lane;
    float4 d0 = make_float4(a0.x - m.x, a0.y - m.y, a0.z - m.z, a0.w - m.w);
    float4 d1 = make_float4(a1.x - m.x, a1.y - m.y, a1.z - m.z, a1.w - m.w);
    float4 d2 = make_float4(a2.x - m.x, a2.y - m.y, a2.z - m.z, a2.w - m.w);
    float4 d3 = make_float4(a3.x - m.x, a3.y - m.y, a3.z - m.z, a3.w - m.w);
    detail[dbase + 0 * E4] = d0;
    detail[dbase + 1 * E4] = d1;
    detail[dbase + 2 * E4] = d2;
    detail[dbase + 3 * E4] = d3;
}

static inline void launch_level(const float* src, const int* idx,
                                float* det, float* mns,
                                int n_out, int n_src, int lg_nout,
                                hipStream_t stream)
{
    int total_rows = Bc * n_out;
    long long threads = (long long)total_rows * E4;
    int blocks = (int)((threads + 255) / 256);
    decomp_level_kernel<<<blocks, 256, 0, stream>>>(
        (const float4*)src, (const int4*)idx,
        (float4*)det, (float4*)mns,
        n_out, n_src, lg_nout, total_rows);
}

extern "C" void kernel_launch(void* const* d_in, const int* in_sizes, int n_in,
                              void* d_out, int out_size, void* d_ws, size_t ws_size,
                              hipStream_t stream)
{
    const float* x    = (const float*)d_in[0];
    const int*   idx0 = (const int*)d_in[1];   // (N/4,   4)
    const int*   idx1 = (const int*)d_in[2];   // (N/16,  4)
    const int*   idx2 = (const int*)d_in[3];   // (N/64,  4)
    const int*   idx3 = (const int*)d_in[4];   // (N/256, 4)

    float* out = (float*)d_out;

    // Output layout: detail0 | detail1 | detail2 | detail3 | means3
    size_t d0_off = 0;
    size_t d1_off = d0_off + (size_t)Bc * Nc        * Ec;  // 67,108,864
    size_t d2_off = d1_off + (size_t)Bc * (Nc / 4)  * Ec;  // +16,777,216
    size_t d3_off = d2_off + (size_t)Bc * (Nc / 16) * Ec;  // +4,194,304
    size_t m3_off = d3_off + (size_t)Bc * (Nc / 64) * Ec;  // +1,048,576

    // Workspace: means0 | means1 | means2  (fp32)
    float* means0 = (float*)d_ws;                                   // B*(N/4)*E
    float* means1 = means0 + (size_t)Bc * (Nc / 4)  * Ec;
    float* means2 = means1 + (size_t)Bc * (Nc / 16) * Ec;

    // Level 0: gather from x (n_src = N), n_out = N/4 (lg = 16)
    launch_level(x,      idx0, out + d0_off, means0,       Nc / 4,   Nc,      16, stream);
    // Level 1
    launch_level(means0, idx1, out + d1_off, means1,       Nc / 16,  Nc / 4,  14, stream);
    // Level 2
    launch_level(means1, idx2, out + d2_off, means2,       Nc / 64,  Nc / 16, 12, stream);
    // Level 3: means go straight to the output tail
    launch_level(means2, idx3, out + d3_off, out + m3_off, Nc / 256, Nc / 64, 10, stream);
}

// Round 3
// 132.480 us; speedup vs baseline: 1.1029x; 1.1029x over previous
//
#include <hip/hip_runtime.h>

// 4-level hierarchical decomposition:
//   sections = src[:, idx, :]  (B, n_out, K=4, E=128)
//   means    = sections.mean(axis=-2)
//   detail   = sections - means  -> (B, n_out*4, E)
// Each 32-thread group handles one (b, r): lane = float4 column (E/4 = 32).
//
// Final outputs (detail0-3, means3) are never re-read -> nontemporal stores,
// keeping L2/L3 capacity for the x gather (dup rows) and ws means re-reads.
// NOTE: __builtin_nontemporal_* needs clang ext_vector types, not HIP float4.

typedef float  f32x4 __attribute__((ext_vector_type(4)));
typedef int    i32x4 __attribute__((ext_vector_type(4)));

constexpr int Bc = 2;
constexpr int Ec = 128;
constexpr int Nc = 262144;
constexpr int E4 = Ec / 4;   // 32 vec4 per row

template <bool NT_MEANS>
__global__ __launch_bounds__(256) void decomp_level_kernel(
    const f32x4* __restrict__ src,    // (B, n_src, E4)
    const i32x4* __restrict__ idx,    // (n_out) int4 (K=4 indices)
    f32x4*       __restrict__ detail, // (B, n_out*4, E4)  [never re-read]
    f32x4*       __restrict__ means,  // (B, n_out, E4)
    int n_out, int n_src, int lg_nout, int total_rows)
{
    int gid  = blockIdx.x * blockDim.x + threadIdx.x;
    int lane = gid & (E4 - 1);
    int row  = gid >> 5;               // (b * n_out + r)
    if (row >= total_rows) return;
    int b = row >> lg_nout;
    int r = row & (n_out - 1);

    const f32x4* s = src + (size_t)b * n_src * E4;
    i32x4 iv = __builtin_nontemporal_load(&idx[r]);

    f32x4 a0 = s[(size_t)iv.x * E4 + lane];
    f32x4 a1 = s[(size_t)iv.y * E4 + lane];
    f32x4 a2 = s[(size_t)iv.z * E4 + lane];
    f32x4 a3 = s[(size_t)iv.w * E4 + lane];

    f32x4 m = (a0 + a1 + a2 + a3) * 0.25f;

    f32x4* mp = &means[((size_t)b * n_out + r) * E4 + lane];
    if (NT_MEANS) __builtin_nontemporal_store(m, mp);
    else          *mp = m;

    size_t dbase = (((size_t)b * n_out + r) * 4) * E4 + lane;
    __builtin_nontemporal_store(a0 - m, &detail[dbase + 0 * E4]);
    __builtin_nontemporal_store(a1 - m, &detail[dbase + 1 * E4]);
    __builtin_nontemporal_store(a2 - m, &detail[dbase + 2 * E4]);
    __builtin_nontemporal_store(a3 - m, &detail[dbase + 3 * E4]);
}

template <bool NT_MEANS>
static inline void launch_level(const float* src, const int* idx,
                                float* det, float* mns,
                                int n_out, int n_src, int lg_nout,
                                hipStream_t stream)
{
    int total_rows = Bc * n_out;
    long long threads = (long long)total_rows * E4;
    int blocks = (int)((threads + 255) / 256);
    decomp_level_kernel<NT_MEANS><<<blocks, 256, 0, stream>>>(
        (const f32x4*)src, (const i32x4*)idx,
        (f32x4*)det, (f32x4*)mns,
        n_out, n_src, lg_nout, total_rows);
}

extern "C" void kernel_launch(void* const* d_in, const int* in_sizes, int n_in,
                              void* d_out, int out_size, void* d_ws, size_t ws_size,
                              hipStream_t stream)
{
    const float* x    = (const float*)d_in[0];
    const int*   idx0 = (const int*)d_in[1];   // (N/4,   4)
    const int*   idx1 = (const int*)d_in[2];   // (N/16,  4)
    const int*   idx2 = (const int*)d_in[3];   // (N/64,  4)
    const int*   idx3 = (const int*)d_in[4];   // (N/256, 4)

    float* out = (float*)d_out;

    // Output layout: detail0 | detail1 | detail2 | detail3 | means3
    size_t d0_off = 0;
    size_t d1_off = d0_off + (size_t)Bc * Nc        * Ec;
    size_t d2_off = d1_off + (size_t)Bc * (Nc / 4)  * Ec;
    size_t d3_off = d2_off + (size_t)Bc * (Nc / 16) * Ec;
    size_t m3_off = d3_off + (size_t)Bc * (Nc / 64) * Ec;

    // Workspace: means0 | means1 | means2  (fp32, re-read next level -> cached)
    float* means0 = (float*)d_ws;
    float* means1 = means0 + (size_t)Bc * (Nc / 4)  * Ec;
    float* means2 = means1 + (size_t)Bc * (Nc / 16) * Ec;

    launch_level<false>(x,      idx0, out + d0_off, means0,       Nc / 4,   Nc,      16, stream);
    launch_level<false>(means0, idx1, out + d1_off, means1,       Nc / 16,  Nc / 4,  14, stream);
    launch_level<false>(means1, idx2, out + d2_off, means2,       Nc / 64,  Nc / 16, 12, stream);
    // Level 3: means go straight to the output tail (never re-read -> NT)
    launch_level<true >(means2, idx3, out + d3_off, out + m3_off, Nc / 256, Nc / 64, 10, stream);
}